// Round 1
// baseline (309.963 us; speedup 1.0000x reference)
//
#include <hip/hip_runtime.h>

#define W 256
#define H 256
#define HW (256*256)
#define NB 12
#define TVEPS 1e-8f
#define NUM_ITER 20

// ws layout (floats):
//   p1  : [NB][2][HW]   offset 0
//   p2  : [NB][2][HW]   offset 2*NB*HW
//   rho : [NB][HW]      offset 4*NB*HW
//   gx  : [NB][HW]      offset 5*NB*HW
//   gy  : [NB][HW]      offset 6*NB*HW

__global__ void precompute_kernel(const float* __restrict__ x,
                                  float* __restrict__ u,
                                  float* __restrict__ ws) {
    const int row = blockIdx.x;          // 0 .. NB*H-1
    const int n = row / H, y = row % H;
    const int xx = threadIdx.x;          // 0 .. 255
    const int idx = y * W + xx;

    const float* __restrict__ I0 = x + (size_t)n * HW;
    const float* __restrict__ I1 = x + (size_t)(NB + n) * HW;

    float* __restrict__ p1  = ws;
    float* __restrict__ p2  = ws + (size_t)2 * NB * HW;
    float* __restrict__ rho = ws + (size_t)4 * NB * HW;
    float* __restrict__ gxp = ws + (size_t)5 * NB * HW;
    float* __restrict__ gyp = ws + (size_t)6 * NB * HW;

    const float i1c = I1[idx];
    const bool xm = xx > 0, xp = xx < W - 1, ym = y > 0, yp = y < H - 1;

    float a00 = 0.f, a01 = 0.f, a02 = 0.f;
    float a10 = 0.f,             a12 = 0.f;
    float a20 = 0.f, a21 = 0.f, a22 = 0.f;
    if (ym) {
        a01 = I1[idx - W];
        if (xm) a00 = I1[idx - W - 1];
        if (xp) a02 = I1[idx - W + 1];
    }
    if (xm) a10 = I1[idx - 1];
    if (xp) a12 = I1[idx + 1];
    if (yp) {
        a21 = I1[idx + W];
        if (xm) a20 = I1[idx + W - 1];
        if (xp) a22 = I1[idx + W + 1];
    }
    // cross-correlation with gx = [[-1,0,1],[-2,0,2],[-1,0,1]]/6
    const float gxv = ((a02 - a00) + 2.f * (a12 - a10) + (a22 - a20)) * (1.f / 6.f);
    // gy = [[-1,-2,-1],[0,0,0],[1,2,1]]/6
    const float gyv = ((a20 - a00) + 2.f * (a21 - a01) + (a22 - a02)) * (1.f / 6.f);

    const size_t np = (size_t)n * HW;
    rho[np + idx] = i1c - I0[idx];
    gxp[np + idx] = gxv;
    gyp[np + idx] = gyv;

    // zero-init state (harness poisons d_out/d_ws with 0xAA)
    u[(size_t)(2 * n) * HW + idx]     = 0.f;
    u[(size_t)(2 * n + 1) * HW + idx] = 0.f;
    p1[(size_t)(2 * n) * HW + idx]     = 0.f;
    p1[(size_t)(2 * n + 1) * HW + idx] = 0.f;
    p2[(size_t)(2 * n) * HW + idx]     = 0.f;
    p2[(size_t)(2 * n + 1) * HW + idx] = 0.f;
}

__global__ void u_kernel(const float* __restrict__ ws,
                         float* __restrict__ u,
                         const float* __restrict__ lam,
                         const float* __restrict__ theta,
                         const float* __restrict__ wxv,
                         const float* __restrict__ wyv) {
    const int row = blockIdx.x;
    const int n = row / H, y = row % H;
    const int xx = threadIdx.x;
    const int idx = y * W + xx;
    const size_t np = (size_t)n * HW;

    const float* __restrict__ p1  = ws;
    const float* __restrict__ p2  = ws + (size_t)2 * NB * HW;
    const float* __restrict__ rho_c = ws + (size_t)4 * NB * HW;
    const float* __restrict__ gxp = ws + (size_t)5 * NB * HW;
    const float* __restrict__ gyp = ws + (size_t)6 * NB * HW;

    const float th0 = theta[0];
    const float tl = th0 * lam[0];
    const float wx0 = wxv[0], wx1 = wxv[1], wx2 = wxv[2];
    const float wy0 = wyv[0], wy1 = wyv[1], wy2 = wyv[2];

    const float gx = gxp[np + idx];
    const float gy = gyp[np + idx];
    float* __restrict__ u0p = u + (size_t)(2 * n) * HW;
    float* __restrict__ u1p = u + (size_t)(2 * n + 1) * HW;
    const float u0 = u0p[idx];
    const float u1 = u1p[idx];

    const float rho = rho_c[np + idx] + gx * u0 + gy * u1;
    const float ng = gx * gx + gy * gy + TVEPS;
    const float th = tl * ng;

    float s0, s1;
    if (fabsf(rho) < th) {
        const float d = rho / ng;
        s0 = d * gx;
        s1 = d * gy;
    } else {
        const float sg = (rho > 0.f) ? 1.f : ((rho < 0.f) ? -1.f : 0.f);
        s0 = tl * gx * sg;
        s1 = tl * gy * sg;
    }
    const float v0 = u0 - s0;
    const float v1 = u1 - s1;

    const float* __restrict__ p1x = p1 + (size_t)(2 * n) * HW;
    const float* __restrict__ p1y = p1 + (size_t)(2 * n + 1) * HW;
    const float* __restrict__ p2x = p2 + (size_t)(2 * n) * HW;
    const float* __restrict__ p2y = p2 + (size_t)(2 * n + 1) * HW;

    float d1 = wx1 * p1x[idx] + wy1 * p1y[idx];
    float d2 = wx1 * p2x[idx] + wy1 * p2y[idx];
    if (xx > 0)     { d1 += wx0 * p1x[idx - 1]; d2 += wx0 * p2x[idx - 1]; }
    if (xx < W - 1) { d1 += wx2 * p1x[idx + 1]; d2 += wx2 * p2x[idx + 1]; }
    if (y > 0)      { d1 += wy0 * p1y[idx - W]; d2 += wy0 * p2y[idx - W]; }
    if (y < H - 1)  { d1 += wy2 * p1y[idx + W]; d2 += wy2 * p2y[idx + W]; }

    u0p[idx] = v0 + th0 * d1;
    u1p[idx] = v1 + th0 * d2;
}

__global__ void p_kernel(const float* __restrict__ u,
                         float* __restrict__ ws,
                         const float* __restrict__ tau,
                         const float* __restrict__ theta) {
    const int row = blockIdx.x;
    const int n = row / H, y = row % H;
    const int xx = threadIdx.x;
    const int idx = y * W + xx;

    float* __restrict__ p1 = ws;
    float* __restrict__ p2 = ws + (size_t)2 * NB * HW;

    const float tt = tau[0] / theta[0];

    const float* __restrict__ u0p = u + (size_t)(2 * n) * HW;
    const float* __restrict__ u1p = u + (size_t)(2 * n + 1) * HW;

    const float c0 = u0p[idx];
    const float g1x = ((xx < W - 1) ? u0p[idx + 1] : 0.f) - c0;
    const float g1y = ((y < H - 1) ? u0p[idx + W] : 0.f) - c0;
    const float c1 = u1p[idx];
    const float g2x = ((xx < W - 1) ? u1p[idx + 1] : 0.f) - c1;
    const float g2y = ((y < H - 1) ? u1p[idx + W] : 0.f) - c1;

    float* __restrict__ p1x = p1 + (size_t)(2 * n) * HW;
    float* __restrict__ p1y = p1 + (size_t)(2 * n + 1) * HW;
    float* __restrict__ p2x = p2 + (size_t)(2 * n) * HW;
    float* __restrict__ p2y = p2 + (size_t)(2 * n + 1) * HW;

    const float den1 = 1.f + tt * (fabsf(g1x) + fabsf(g1y));
    p1x[idx] = (p1x[idx] + tt * g1x) / den1;
    p1y[idx] = (p1y[idx] + tt * g1y) / den1;
    const float den2 = 1.f + tt * (fabsf(g2x) + fabsf(g2y));
    p2x[idx] = (p2x[idx] + tt * g2x) / den2;
    p2y[idx] = (p2y[idx] + tt * g2y) / den2;
}

extern "C" void kernel_launch(void* const* d_in, const int* in_sizes, int n_in,
                              void* d_out, int out_size, void* d_ws, size_t ws_size,
                              hipStream_t stream) {
    const float* x     = (const float*)d_in[0];
    const float* lam   = (const float*)d_in[1];
    const float* tau   = (const float*)d_in[2];
    const float* theta = (const float*)d_in[3];
    const float* wxv   = (const float*)d_in[4];
    const float* wyv   = (const float*)d_in[5];
    float* u  = (float*)d_out;
    float* ws = (float*)d_ws;

    const dim3 grid(NB * H);
    const dim3 block(W);

    precompute_kernel<<<grid, block, 0, stream>>>(x, u, ws);
    for (int it = 0; it < NUM_ITER; ++it) {
        u_kernel<<<grid, block, 0, stream>>>(ws, u, lam, theta, wxv, wyv);
        p_kernel<<<grid, block, 0, stream>>>(u, ws, tau, theta);
    }
}